// Round 5
// baseline (28390.799 us; speedup 1.0000x reference)
//
#include <hip/hip_runtime.h>
#include <math.h>

// ---------------------------------------------------------------------------
// Decoder: 3-layer LSTM + dot attention + MLP + CE loss.  B=16, T=257, H=1024.
// Round 5: PERSISTENT recurrence kernel.
//   - 384 WGs x 512 thr, all co-resident (launch_bounds(512,4) -> <=128 VGPR
//     -> 2 WGs/CU capacity; 384 <= 512). One WG = 8 units x 4 gates of one
//     cell; its weight slice (bf16) lives in 64 VGPRs/thread, loaded once
//     from the fp32 inputs. c-state in registers.
//   - device barrier per diagonal: per-WG release flag -> master WG polls ->
//     gen broadcast. __threadfence() (agent wbL2) before arrival.
//   - h0/h1/h2 as full write-once histories => no stale-L2 reads across XCDs.
//   - epilogue: r4's bf16 MFMA NT-GEMM path, buffers re-laid out (70.6 MB).
// ---------------------------------------------------------------------------

namespace {
constexpr int TT = 257;
constexpr int BT = 4112;
constexpr int NWG = 384;

// bf16 element offsets
constexpr size_t OFF_H0H  = 0;               // [258][16][1024]
constexpr size_t OFF_H1H  = 4227072;         // [258][16][1024]
constexpr size_t OFF_H2B  = 8454144;         // [258][16][1024]
constexpr size_t OFF_EMBB = 12681216;        // [1024][512]
constexpr size_t OFF_SC   = 13205504;        // [16][257][512]
constexpr size_t OFF_CTX  = 15310848;        // [16][257][1024]
constexpr size_t OFF_HID  = 19521536;        // [4112][1024]
constexpr size_t OFF_LG   = OFF_SC;          // alias (sc dead at logits)
constexpr size_t OFF_ENCB = 0;               // alias over h0h/h1h (dead после recurrence)
constexpr size_t OFF_ENCT = 23732224;        // [16][1024][512]
constexpr size_t OFF_W1B  = 32120832;        // [1024][2048]
constexpr size_t OFF_W2B  = 34217984;        // [1024][1024]
constexpr size_t END_BF   = 35266560;
constexpr size_t OFF_INT_BYTES = END_BF * 2;            // 3 x 4112 ints
constexpr size_t OFF_BAR_BYTES = OFF_INT_BYTES + 49344; // gen + 384 flags
constexpr size_t TOTAL_BYTES   = OFF_BAR_BYTES + 1540;  // 70,584,004
}

typedef __attribute__((ext_vector_type(8))) short bf16x8;
typedef __attribute__((ext_vector_type(4))) float f32x4;

__device__ __forceinline__ float bf2f(ushort u) {
    union { unsigned int v; float f; } x; x.v = ((unsigned int)u) << 16; return x.f;
}
__device__ __forceinline__ ushort f2bf(float f) {
    union { float f; unsigned int v; } x; x.f = f;
    return (ushort)((x.v + 0x7fff + ((x.v >> 16) & 1)) >> 16);
}
__device__ __forceinline__ float sigm(float x) { return 1.f / (1.f + __expf(-x)); }

// ---------------------------------------------------------------------------
__global__ void k_fail(float* out) { out[0] = -123456.0f; }

// ---------------------------------------------------------------------------
__global__ __launch_bounds__(256) void k_init(const int* __restrict__ tokens,
                                              ushort* __restrict__ wsb,
                                              float* __restrict__ out)
{
    int i = blockIdx.x * 256 + threadIdx.x;          // 65536 threads
    int* dec_in  = (int*)((char*)wsb + OFF_INT_BYTES);
    int* dec_out = dec_in + 4112;
    int* hsrow   = dec_in + 8224;
    unsigned* bar = (unsigned*)((char*)wsb + OFF_BAR_BYTES);
    if (i < 4112) {
        int t = i >> 4, b = i & 15;                  // t-major
        dec_in[i] = (t == 0) ? 1 : tokens[b * 256 + (t - 1)];
        int bb = i / 257, tt = i % 257;              // m-order (b-major)
        dec_out[i] = (tt < 256) ? tokens[bb * 256 + tt] : 2;
        hsrow[i] = (tt + 1) * 16 + bb;
    }
    if (i < 16384) {                                  // zero history slot 0
        wsb[OFF_H0H + i] = 0;
        wsb[OFF_H1H + i] = 0;
        wsb[OFF_H2B + i] = 0;
    }
    if (i < 385) bar[i] = 0;
    if (i == 0) out[0] = 0.f;
}

// ---------------------------------------------------------------------------
// generic contiguous fp32 -> bf16 (n = grid.x * 2048 elems)
__global__ __launch_bounds__(256) void k_cvt_flat(const float* __restrict__ src,
                                                  ushort* __restrict__ dst)
{
    size_t e = ((size_t)blockIdx.x * 256 + threadIdx.x) * 8;
    float4 a = *(const float4*)(src + e);
    float4 b = *(const float4*)(src + e + 4);
    uint4 o;
    o.x = (unsigned)f2bf(a.x) | ((unsigned)f2bf(a.y) << 16);
    o.y = (unsigned)f2bf(a.z) | ((unsigned)f2bf(a.w) << 16);
    o.z = (unsigned)f2bf(b.x) | ((unsigned)f2bf(b.y) << 16);
    o.w = (unsigned)f2bf(b.z) | ((unsigned)f2bf(b.w) << 16);
    *(uint4*)(dst + e) = o;
}

// ---------------------------------------------------------------------------
// encT[b][h][s] = bf16(enc[b][s][h]).  grid (16, 32, 16), block 256.
__global__ __launch_bounds__(256) void k_enc_t(const float* __restrict__ enc,
                                               ushort* __restrict__ encT)
{
    __shared__ float tile[32][33];
    int b = blockIdx.z, s0 = blockIdx.x * 32, h0 = blockIdx.y * 32;
    int tx = threadIdx.x & 31, ty = threadIdx.x >> 5;
    const float* src = enc + (size_t)b * 524288;
    #pragma unroll
    for (int i = 0; i < 4; i++)
        tile[ty + i * 8][tx] = src[(size_t)(s0 + ty + i * 8) * 1024 + h0 + tx];
    __syncthreads();
    ushort* dst = encT + (size_t)b * 524288;
    #pragma unroll
    for (int i = 0; i < 4; i++)
        dst[(size_t)(h0 + ty + i * 8) * 512 + s0 + tx] = f2bf(tile[tx][ty + i * 8]);
}

// ---------------------------------------------------------------------------
// Persistent recurrence. 384 WGs x 512 thr. WG -> (cell = wg>>7, wloc = wg&127).
// Owns units [wloc*8, wloc*8+8) x 4 gates. Weight rows (bf16) in registers:
// wave w covers concat-K [w*span, w*span+span) where concat = hh (K=1024) then
// ih/x (K=1024, cell0: 512 + pad). rowgroup rg: gate = rg*2 + (l15>>3),
// unit = u0 + (l15&7). One device barrier per diagonal.
__global__ __launch_bounds__(512, 4) void k_rec_persist(
    const float* __restrict__ Wih0, const float* __restrict__ Whh0,
    const float* __restrict__ Wih1, const float* __restrict__ Whh1,
    const float* __restrict__ Wih2, const float* __restrict__ Whh2,
    const float* __restrict__ bih0, const float* __restrict__ bhh0,
    const float* __restrict__ bih1, const float* __restrict__ bhh1,
    const float* __restrict__ bih2, const float* __restrict__ bhh2,
    const ushort* __restrict__ embB, ushort* __restrict__ h0h,
    ushort* __restrict__ h1h, ushort* __restrict__ h2b,
    const int* __restrict__ dec_in, unsigned* __restrict__ bar)
{
    __shared__ float part[8][2][16][16];   // [wave][rg][b][n]  16 KB
    __shared__ float gsum[4][8][16];       // [gate][u][b]       2 KB
    int wg = blockIdx.x;
    int cell = wg >> 7, wloc = wg & 127;
    int u0 = wloc * 8;
    int tid = threadIdx.x;
    int w = __builtin_amdgcn_readfirstlane(tid) >> 6;   // wave id (scalar)
    int lane = tid & 63, l15 = lane & 15, quad = lane >> 4;
    int rowA = ((l15 >> 3) * 1024) + u0 + (l15 & 7);    // rg0: gates 0/1
    int rows[2] = { rowA, rowA + 2048 };                // rg1: gates 2/3

    const float* WihP = (cell == 0) ? Wih0 : (cell == 1) ? Wih1 : Wih2;
    const float* WhhP = (cell == 0) ? Whh0 : (cell == 1) ? Whh1 : Whh2;
    const float* biP  = (cell == 0) ? bih0 : (cell == 1) ? bih1 : bih2;
    const float* bhP  = (cell == 0) ? bhh0 : (cell == 1) ? bhh1 : bhh2;
    int ldih = (cell == 0) ? 1536 : 1024;
    int span = (cell == 0) ? 192 : 256;
    int nit  = (cell == 0) ? 6 : 8;

    // ---- one-time weight preload: fp32 -> bf16 registers ----
    bf16x8 wreg[2][8];
    #pragma unroll
    for (int rg = 0; rg < 2; rg++) {
        #pragma unroll
        for (int i = 0; i < 8; i++) {
            if (i < nit) {
                int gk = w * span + i * 32;
                const float* src = (gk < 1024)
                    ? WhhP + (size_t)rows[rg] * 1024 + gk + quad * 8
                    : WihP + (size_t)rows[rg] * ldih + (gk - 1024) + quad * 8;
                float4 x0 = *(const float4*)src;
                float4 x1 = *(const float4*)(src + 4);
                bf16x8 v;
                v[0] = (short)f2bf(x0.x); v[1] = (short)f2bf(x0.y);
                v[2] = (short)f2bf(x0.z); v[3] = (short)f2bf(x0.w);
                v[4] = (short)f2bf(x1.x); v[5] = (short)f2bf(x1.y);
                v[6] = (short)f2bf(x1.z); v[7] = (short)f2bf(x1.w);
                wreg[rg][i] = v;
            }
        }
    }
    // bias sum for this thread's reduction slot
    float bsum;
    {
        int rg = tid >> 8, nn = tid & 15;
        int g = rg * 2 + (nn >> 3), u = nn & 7;
        int bidx = g * 1024 + u0 + u;
        bsum = biP[bidx] + bhP[bidx];
    }
    float cstate = 0.f;

    for (int d = 0; d < 259; d++) {
        int t = d - cell;
        if (t >= 0 && t < TT) {
            const ushort* hhA; const ushort* ihA = nullptr; ushort* hdst;
            if (cell == 0) {
                hhA = h0h + (size_t)d * 16384;
                hdst = h0h + (size_t)(d + 1) * 16384;
            } else if (cell == 1) {
                ihA = h0h + (size_t)d * 16384;
                hhA = h1h + (size_t)(d - 1) * 16384;
                hdst = h1h + (size_t)d * 16384;
            } else {
                ihA = h1h + (size_t)(d - 1) * 16384;
                hhA = h2b + (size_t)(d - 2) * 16384;
                hdst = h2b + (size_t)(d - 1) * 16384;
            }
            const ushort* embRow = nullptr;
            if (cell == 0)
                embRow = embB + (size_t)dec_in[d * 16 + l15] * 512;

            f32x4 acc0 = {0.f, 0.f, 0.f, 0.f}, acc1 = {0.f, 0.f, 0.f, 0.f};
            #pragma unroll
            for (int i = 0; i < 8; i++) {
                if (i < nit) {
                    int gk = w * span + i * 32;
                    bf16x8 af;
                    if (gk < 1024)
                        af = *(const bf16x8*)(hhA + l15 * 1024 + gk + quad * 8);
                    else if (cell == 0)
                        af = *(const bf16x8*)(embRow + (gk - 1024) + quad * 8);
                    else
                        af = *(const bf16x8*)(ihA + l15 * 1024 + (gk - 1024) + quad * 8);
                    acc0 = __builtin_amdgcn_mfma_f32_16x16x32_bf16(af, wreg[0][i], acc0, 0, 0, 0);
                    acc1 = __builtin_amdgcn_mfma_f32_16x16x32_bf16(af, wreg[1][i], acc1, 0, 0, 0);
                }
            }
            #pragma unroll
            for (int r = 0; r < 4; r++) {
                part[w][0][quad * 4 + r][l15] = acc0[r];
                part[w][1][quad * 4 + r][l15] = acc1[r];
            }
            __syncthreads();
            {
                int rg = tid >> 8, b = (tid >> 4) & 15, nn = tid & 15;
                float s = bsum;
                #pragma unroll
                for (int ww = 0; ww < 8; ww++) s += part[ww][rg][b][nn];
                gsum[rg * 2 + (nn >> 3)][nn & 7][b] = s;
            }
            __syncthreads();
            if (tid < 128) {
                int b = tid >> 3, u = tid & 7;
                float ig = sigm(gsum[0][u][b]);
                float fg = sigm(gsum[1][u][b]);
                float gg = tanhf(gsum[2][u][b]);
                float og = sigm(gsum[3][u][b]);
                cstate = fg * cstate + ig * gg;
                hdst[b * 1024 + u0 + u] = f2bf(og * tanhf(cstate));
            }
        }
        if (d == 258) break;
        // ---- device barrier ----
        __threadfence();                     // push h-stores to agent scope
        __syncthreads();
        unsigned target = (unsigned)(d + 1);
        if (tid == 0)
            __hip_atomic_store(&bar[1 + wg], target, __ATOMIC_RELEASE,
                               __HIP_MEMORY_SCOPE_AGENT);
        if (wg == 0) {
            if (tid < NWG)
                while (__hip_atomic_load(&bar[1 + tid], __ATOMIC_ACQUIRE,
                                         __HIP_MEMORY_SCOPE_AGENT) < target)
                    __builtin_amdgcn_s_sleep(1);
            __syncthreads();
            if (tid == 0)
                __hip_atomic_store(&bar[0], target, __ATOMIC_RELEASE,
                                   __HIP_MEMORY_SCOPE_AGENT);
        } else {
            if (tid == 0)
                while (__hip_atomic_load(&bar[0], __ATOMIC_ACQUIRE,
                                         __HIP_MEMORY_SCOPE_AGENT) < target)
                    __builtin_amdgcn_s_sleep(1);
            __syncthreads();
        }
    }
}

// ---------------------------------------------------------------------------
// bf16 MFMA NT-GEMM: C[M,N] (+)= A @ B^T.  64x64 tile, 4 waves, direct
// fragment loads. A row gather via aIdx (nullable). Batched via blockIdx.z.
__global__ __launch_bounds__(256) void k_gemm_bb(
    const ushort* __restrict__ A, int lda, long sA, const int* __restrict__ aIdx,
    const ushort* __restrict__ B, int ldb, long sB,
    ushort* __restrict__ C, int ldc, long sC,
    int M, int K, int accum)
{
    int z = blockIdx.z;
    const ushort* Ab = A + (size_t)z * sA;
    const ushort* Bb = B + (size_t)z * sB;
    ushort* Cb = C + (size_t)z * sC;
    int m0 = blockIdx.y * 64, n0 = blockIdx.x * 64;
    int tid = threadIdx.x, w = tid >> 6, lane = tid & 63;
    int l15 = lane & 15, quad = lane >> 4;
    int am = m0 + w * 16 + l15;
    int ar = (am < M) ? (aIdx ? aIdx[am] : am) : (aIdx ? aIdx[0] : 0);
    const ushort* ap = Ab + (size_t)ar * lda + quad * 8;
    const ushort* bp = Bb + (size_t)(n0 + l15) * ldb + quad * 8;
    f32x4 acc[4] = {{0.f,0.f,0.f,0.f},{0.f,0.f,0.f,0.f},{0.f,0.f,0.f,0.f},{0.f,0.f,0.f,0.f}};
    for (int k0 = 0; k0 < K; k0 += 32) {
        bf16x8 af = *(const bf16x8*)(ap + k0);
        #pragma unroll
        for (int j = 0; j < 4; j++) {
            bf16x8 bfb = *(const bf16x8*)(bp + (size_t)j * 16 * ldb + k0);
            acc[j] = __builtin_amdgcn_mfma_f32_16x16x32_bf16(af, bfb, acc[j], 0, 0, 0);
        }
    }
    #pragma unroll
    for (int j = 0; j < 4; j++)
        #pragma unroll
        for (int r = 0; r < 4; r++) {
            int row = m0 + w * 16 + quad * 4 + r;
            if (row < M) {
                ushort* cp = Cb + (size_t)row * ldc + n0 + j * 16 + l15;
                float v = acc[j][r];
                if (accum) v += bf2f(*cp);
                *cp = f2bf(v);
            }
        }
}

// ---------------------------------------------------------------------------
__global__ __launch_bounds__(256) void k_softmax_b(ushort* __restrict__ sc)
{
    __shared__ float red[4];
    ushort* p = sc + (size_t)blockIdx.x * 512;
    int tid = threadIdx.x;
    float a = bf2f(p[tid]), b = bf2f(p[tid + 256]);
    float m = fmaxf(a, b);
    for (int o = 32; o; o >>= 1) m = fmaxf(m, __shfl_xor(m, o, 64));
    if ((tid & 63) == 0) red[tid >> 6] = m;
    __syncthreads();
    m = fmaxf(fmaxf(red[0], red[1]), fmaxf(red[2], red[3]));
    __syncthreads();
    float ea = __expf(a - m), eb = __expf(b - m);
    float s = ea + eb;
    for (int o = 32; o; o >>= 1) s += __shfl_xor(s, o, 64);
    if ((tid & 63) == 0) red[tid >> 6] = s;
    __syncthreads();
    s = red[0] + red[1] + red[2] + red[3];
    float inv = 1.f / s;
    p[tid] = f2bf(ea * inv);
    p[tid + 256] = f2bf(eb * inv);
}

// ---------------------------------------------------------------------------
__global__ __launch_bounds__(256) void k_tanh_bias_b(ushort* __restrict__ hid,
                                                     const float* __restrict__ b1)
{
    size_t i = (size_t)blockIdx.x * 256 + threadIdx.x;
    hid[i] = f2bf(tanhf(bf2f(hid[i]) + b1[i & 1023]));
}

// ---------------------------------------------------------------------------
__global__ __launch_bounds__(256) void k_loss_b(const ushort* __restrict__ logits,
                                                const float* __restrict__ b2,
                                                const int* __restrict__ dec_out_m,
                                                float* __restrict__ out)
{
    __shared__ float red[4];
    int m = blockIdx.x;
    const ushort* p = logits + (size_t)m * 1024;
    int tid = threadIdx.x;
    float v0 = bf2f(p[tid]) + b2[tid];
    float v1 = bf2f(p[tid + 256]) + b2[tid + 256];
    float v2 = bf2f(p[tid + 512]) + b2[tid + 512];
    float v3 = bf2f(p[tid + 768]) + b2[tid + 768];
    float mx = fmaxf(fmaxf(v0, v1), fmaxf(v2, v3));
    for (int o = 32; o; o >>= 1) mx = fmaxf(mx, __shfl_xor(mx, o, 64));
    if ((tid & 63) == 0) red[tid >> 6] = mx;
    __syncthreads();
    mx = fmaxf(fmaxf(red[0], red[1]), fmaxf(red[2], red[3]));
    __syncthreads();
    float s = __expf(v0 - mx) + __expf(v1 - mx) + __expf(v2 - mx) + __expf(v3 - mx);
    for (int o = 32; o; o >>= 1) s += __shfl_xor(s, o, 64);
    if ((tid & 63) == 0) red[tid >> 6] = s;
    __syncthreads();
    if (tid == 0) {
        float ssum = red[0] + red[1] + red[2] + red[3];
        int tgt = dec_out_m[m];
        float tv = bf2f(p[tgt]) + b2[tgt];
        atomicAdd(out, (mx + logf(ssum) - tv) * (1.0f / 4112.0f));
    }
}

// ---------------------------------------------------------------------------
extern "C" void kernel_launch(void* const* d_in, const int* in_sizes, int n_in,
                              void* d_out, int out_size, void* d_ws, size_t ws_size,
                              hipStream_t stream)
{
    const int*   tokens = (const int*)d_in[0];
    const float* enc    = (const float*)d_in[1];
    const float* emb    = (const float*)d_in[2];
    const float* Wih0   = (const float*)d_in[3];
    const float* Whh0   = (const float*)d_in[4];
    const float* bih0   = (const float*)d_in[5];
    const float* bhh0   = (const float*)d_in[6];
    const float* Wih1   = (const float*)d_in[7];
    const float* Whh1   = (const float*)d_in[8];
    const float* bih1   = (const float*)d_in[9];
    const float* bhh1   = (const float*)d_in[10];
    const float* Wih2   = (const float*)d_in[11];
    const float* Whh2   = (const float*)d_in[12];
    const float* bih2   = (const float*)d_in[13];
    const float* bhh2   = (const float*)d_in[14];
    const float* W1     = (const float*)d_in[15];
    const float* b1     = (const float*)d_in[16];
    const float* W2     = (const float*)d_in[17];
    const float* b2     = (const float*)d_in[18];

    float* out = (float*)d_out;
    if (ws_size < TOTAL_BYTES) { k_fail<<<1, 1, 0, stream>>>(out); return; }

    ushort* wsb  = (ushort*)d_ws;
    ushort* h0h  = wsb + OFF_H0H;
    ushort* h1h  = wsb + OFF_H1H;
    ushort* h2b  = wsb + OFF_H2B;
    ushort* embB = wsb + OFF_EMBB;
    ushort* sc   = wsb + OFF_SC;
    ushort* ctx  = wsb + OFF_CTX;
    ushort* hid  = wsb + OFF_HID;
    ushort* lg   = wsb + OFF_LG;
    ushort* encB = wsb + OFF_ENCB;
    ushort* encT = wsb + OFF_ENCT;
    ushort* W1b  = wsb + OFF_W1B;
    ushort* W2b  = wsb + OFF_W2B;
    int* dec_in  = (int*)((char*)d_ws + OFF_INT_BYTES);
    int* dec_out = dec_in + 4112;
    int* hsrow   = dec_in + 8224;
    unsigned* bar = (unsigned*)((char*)d_ws + OFF_BAR_BYTES);

    k_init<<<256, 256, 0, stream>>>(tokens, wsb, out);
    k_cvt_flat<<<256, 256, 0, stream>>>(emb, embB);

    k_rec_persist<<<NWG, 512, 0, stream>>>(Wih0, Whh0, Wih1, Whh1, Wih2, Whh2,
                                           bih0, bhh0, bih1, bhh1, bih2, bhh2,
                                           embB, h0h, h1h, h2b, dec_in, bar);

    // epilogue conversions (encB aliases dead h0h/h1h region)
    k_cvt_flat<<<4096, 256, 0, stream>>>(enc, encB);
    k_enc_t<<<dim3(16, 32, 16), 256, 0, stream>>>(enc, encT);
    k_cvt_flat<<<1024, 256, 0, stream>>>(W1, W1b);
    k_cvt_flat<<<512, 256, 0, stream>>>(W2, W2b);

    // scores[b][t][s] = h2(t) . enc[b,s]
    k_gemm_bb<<<dim3(8, 5, 16), 256, 0, stream>>>(h2b + 16384, 16384, 1024, nullptr,
                                                  encB, 1024, 524288,
                                                  sc, 512, 131584, TT, 1024, 0);
    k_softmax_b<<<4112, 256, 0, stream>>>(sc);
    // ctx[b][t][h] = attn . encT[b][h]
    k_gemm_bb<<<dim3(16, 5, 16), 256, 0, stream>>>(sc, 512, 131584, nullptr,
                                                   encT, 512, 524288,
                                                   ctx, 1024, 263168, TT, 512, 0);
    // hidden = hs @ W1[:, :1024]^T + ctx @ W1[:, 1024:]^T, then tanh(+b1)
    k_gemm_bb<<<dim3(16, 65, 1), 256, 0, stream>>>(h2b, 1024, 0, hsrow,
                                                   W1b, 2048, 0,
                                                   hid, 1024, 0, BT, 1024, 0);
    k_gemm_bb<<<dim3(16, 65, 1), 256, 0, stream>>>(ctx, 1024, 0, nullptr,
                                                   W1b + 1024, 2048, 0,
                                                   hid, 1024, 0, BT, 1024, 1);
    k_tanh_bias_b<<<16448, 256, 0, stream>>>(hid, b1);
    // logits = hidden @ W2^T ; loss
    k_gemm_bb<<<dim3(16, 65, 1), 256, 0, stream>>>(hid, 1024, 0, nullptr,
                                                   W2b, 1024, 0,
                                                   lg, 1024, 0, BT, 1024, 0);
    k_loss_b<<<4112, 256, 0, stream>>>(lg, b2, dec_out, out);
}